// Round 11
// baseline (326.972 us; speedup 1.0000x reference)
//
#include <hip/hip_runtime.h>
#include <hip/hip_fp16.h>
#include <math.h>

#define D 64
#define NUM_USERS 100000
#define NUM_ITEMS 50000
#define N_NODES 150000   // NUM_USERS + NUM_ITEMS
#define NNZ 2400000
#define BATCH 8192
#define NEG_SLOPE 0.1f
#define EPS_NRM 1e-12f

// bucket geometry: bucket = row >> 9 (512 rows/bucket)
#define NB2     293                 // ceil(150000/512)
#define RPB     512                 // rows per bucket
#define NCHUNK  256
#define CH      9376                // chunk elems; 16B-aligned bases
#define CAPB    9472                // fixed per-bucket region (mean 8192, +14 sigma)
#define HCAP    4736                // per half-bucket output region (mean 4096, +10 sigma)
#define CAPH    5120                // LDS sorted-buffer capacity per half (20 KB)
#define VSCALE  16383.f             // 14-bit val quantization

typedef unsigned short ushort_t;
// clang native vectors: __builtin_nontemporal_load requires these (HIP_vector_type invalid)
typedef int   iv4 __attribute__((ext_vector_type(4)));
typedef float fv4 __attribute__((ext_vector_type(4)));

__device__ __forceinline__ float wave_sum64(float v) {
    #pragma unroll
    for (int off = 32; off > 0; off >>= 1)
        v += __shfl_xor(v, off, 64);
    return v;
}

// fp16 helpers: extraction folds into v_fma_mix_f32 (op_sel) when fused.
__device__ __forceinline__ float h2f_lo(unsigned u) {
    return __half2float(__ushort_as_half((unsigned short)(u & 0xFFFFu)));
}
__device__ __forceinline__ float h2f_hi(unsigned u) {
    return __half2float(__ushort_as_half((unsigned short)(u >> 16)));
}

// ---------- CSR build: direct-reservation bucket scatter (no hist/scan kernels) ----
// Blocks [0, NCHUNK): per-chunk LDS count -> one global atomicAdd per bucket to
// reserve a run in the bucket's fixed CAPB region -> write 8B uint2 entries.
// Blocks [NCHUNK, ...): init (lrelu+L2norm of prefs -> fp16 p0), fills idle CUs.
__global__ void __launch_bounds__(1024) scatter_init(
        const int* __restrict__ rows, const int* __restrict__ cols,
        const float* __restrict__ vals, int* __restrict__ gcur,
        uint2* __restrict__ es8,
        const float* __restrict__ upref, const float* __restrict__ ipref,
        __half* __restrict__ p0) {
    __shared__ int cnt[NB2];
    __shared__ int cur[NB2];
    int blk = blockIdx.x, tid = threadIdx.x;

    if (blk >= NCHUNK) {
        // ---- init part: one row per wave, 16 rows per block ----
        int row  = (blk - NCHUNK) * 16 + (tid >> 6);
        int lane = tid & 63;
        if (row >= N_NODES) return;
        float x = (row < NUM_USERS) ? upref[(size_t)row * D + lane]
                                    : ipref[(size_t)(row - NUM_USERS) * D + lane];
        x = (x >= 0.f) ? x : NEG_SLOPE * x;
        float norm = sqrtf(wave_sum64(x * x));
        float y = x / fmaxf(norm, EPS_NRM);
        p0[(size_t)row * D + lane] = __float2half(y);
        return;
    }

    // ---- scatter part ----
    for (int b = tid; b < NB2; b += 1024) cnt[b] = 0;
    __syncthreads();
    int base = blk * CH;
    int n = NNZ - base; if (n > CH) n = CH;      // always divisible by 4
    const iv4* r4 = (const iv4*)(rows + base);
    for (int i = tid; i < (n >> 2); i += 1024) {
        iv4 r = r4[i];                           // normal load: L2-warm for pass 2
        atomicAdd(&cnt[r.x >> 9], 1);
        atomicAdd(&cnt[r.y >> 9], 1);
        atomicAdd(&cnt[r.z >> 9], 1);
        atomicAdd(&cnt[r.w >> 9], 1);
    }
    __syncthreads();
    if (tid < NB2) {
        int c = cnt[tid];
        int off = (c > 0) ? atomicAdd(&gcur[tid], c) : 0;   // reserve run
        cur[tid] = tid * CAPB + off;
    }
    __syncthreads();
    const iv4* c4 = (const iv4*)(cols + base);
    const fv4* v4 = (const fv4*)(vals + base);
    for (int i = tid; i < (n >> 2); i += 1024) {
        iv4 r  = r4[i];                          // L2 hit
        iv4 cc = __builtin_nontemporal_load(&c4[i]);
        fv4 v  = __builtin_nontemporal_load(&v4[i]);
        int p;
        p = atomicAdd(&cur[r.x >> 9], 1);
        es8[p] = make_uint2((unsigned)cc.x | ((unsigned)(v.x * VSCALE + 0.5f) << 18),
                            (unsigned)(r.x & (RPB - 1)));
        p = atomicAdd(&cur[r.y >> 9], 1);
        es8[p] = make_uint2((unsigned)cc.y | ((unsigned)(v.y * VSCALE + 0.5f) << 18),
                            (unsigned)(r.y & (RPB - 1)));
        p = atomicAdd(&cur[r.z >> 9], 1);
        es8[p] = make_uint2((unsigned)cc.z | ((unsigned)(v.z * VSCALE + 0.5f) << 18),
                            (unsigned)(r.z & (RPB - 1)));
        p = atomicAdd(&cur[r.w >> 9], 1);
        es8[p] = make_uint2((unsigned)cc.w | ((unsigned)(v.w * VSCALE + 0.5f) << 18),
                            (unsigned)(r.w & (RPB - 1)));
    }
}

// TWO blocks per bucket: block handles rows [h*256, h*256+256) of bucket b
// (h = blk&1, b = blk>>1). Scans the full bucket region, histograms/permutes
// only its half's keys, outputs to its own HCAP half-region. 512 threads,
// ~21 KB LDS -> 4 blocks/CU (was 293 blocks x 1024 thr at 50% occ, latency-bound).
__global__ void __launch_bounds__(512) bucket_sort(const uint2* __restrict__ es8,
                                                   const int* __restrict__ gcur,
                                                   unsigned* __restrict__ es,
                                                   int2* __restrict__ rowptr2) {
    __shared__ int      hist[256];
    __shared__ int      wsum[4];
    __shared__ unsigned outbuf[CAPH];   // 20 KB
    __shared__ int      sh_total;
    int blk = blockIdx.x, tid = threadIdx.x;
    int b = blk >> 1, h = blk & 1;
    int base = b * CAPB;
    int fill = gcur[b];
    int end  = base + fill;
    int obase = base + h * HCAP;        // this half's output region
    if (tid < 256) hist[tid] = 0;
    __syncthreads();
    for (int i = base + tid; i < end; i += 512) {
        unsigned k = es8[i].y;
        if ((int)(k >> 8) == h) atomicAdd(&hist[k & 255], 1);
    }
    __syncthreads();
    int excl = 0, v = 0;
    if (tid < 256) {
        v = hist[tid];
        int lane = tid & 63, w = tid >> 6;
        int s = v;
        #pragma unroll
        for (int off = 1; off < 64; off <<= 1) {
            int t = __shfl_up(s, off, 64);
            if (lane >= off) s += t;
        }
        if (lane == 63) wsum[w] = s;
        excl = s - v;
    }
    __syncthreads();
    if (tid == 0) {
        int a = 0;
        #pragma unroll
        for (int i = 0; i < 4; i++) { int t = wsum[i]; wsum[i] = a; a += t; }
    }
    __syncthreads();
    if (tid < 256) {
        excl += wsum[tid >> 6];
        int r = b * RPB + h * 256 + tid;
        if (r < N_NODES)
            rowptr2[r] = make_int2(obase + excl, obase + excl + v);
        if (tid == 255) sh_total = excl + v;
        hist[tid] = excl;           // reuse as cursor (half-relative)
    }
    __syncthreads();
    for (int i = base + tid; i < end; i += 512) {
        uint2 kv = es8[i];                      // L2-warm re-read
        if ((int)(kv.y >> 8) == h) {
            int d = atomicAdd(&hist[kv.y & 255], 1);   // LDS int atomic
            outbuf[d] = kv.x;                   // final 4B format
        }
    }
    __syncthreads();
    int total = sh_total;
    for (int i = tid; i < total; i += 512)
        es[obase + i] = outbuf[i];              // coalesced dump
}

// ---------- GCN ----------
__device__ __forceinline__ void acc8(float a[8], float v, uint4 q) {
    a[0] = fmaf(v, h2f_lo(q.x), a[0]);
    a[1] = fmaf(v, h2f_hi(q.x), a[1]);
    a[2] = fmaf(v, h2f_lo(q.y), a[2]);
    a[3] = fmaf(v, h2f_hi(q.y), a[3]);
    a[4] = fmaf(v, h2f_lo(q.z), a[4]);
    a[5] = fmaf(v, h2f_hi(q.z), a[5]);
    a[6] = fmaf(v, h2f_lo(q.w), a[6]);
    a[7] = fmaf(v, h2f_hi(q.w), a[7]);
}

// TWO rows per wave (32 lanes each): 4 edge-slots (sub = hl>>3), 8 features/lane
// (fl = hl&7); 2x unrolled; es entries are 4B packed col(18)|valq(14); p is fp16.
// Epilogue: 2-level transpose-butterfly over sub bits arranged so lane (sub,fl)
// ends holding ADJACENT features fl*8+2*sub, +1 -> one packed __half2 store.
__global__ void gather_kernel(const int2* __restrict__ rowptr2,
                              const unsigned* __restrict__ es,
                              const __half* __restrict__ p,
                              __half* __restrict__ pn) {
    int tid  = threadIdx.x;
    int row  = blockIdx.x * 8 + (tid >> 5);     // 8 rows per 256-thread block
    if (row >= N_NODES) return;
    int hl   = tid & 31;
    int sub  = hl >> 3;       // 0..3 edge slot
    int fl   = hl & 7;        // feature-octet index
    int2 rp  = rowptr2[row];
    int beg = rp.x, end = rp.y;

    float a[8];
    #pragma unroll
    for (int k = 0; k < 8; k++) a[k] = 0.f;

    const float vs = 1.f / VSCALE;
    int e = beg + sub;
    while (e + 4 < end) {
        unsigned ev0 = es[e];
        unsigned ev1 = es[e + 4];
        const uint4 q0 = *(const uint4*)(p + (((ev0 & 0x3FFFFu) << 6) | (fl << 3)));
        const uint4 q1 = *(const uint4*)(p + (((ev1 & 0x3FFFFu) << 6) | (fl << 3)));
        float v0 = (float)(ev0 >> 18) * vs;
        float v1 = (float)(ev1 >> 18) * vs;
        acc8(a, v0, q0);
        acc8(a, v1, q1);
        e += 8;
    }
    if (e < end) {
        unsigned ev = es[e];
        const uint4 q = *(const uint4*)(p + (((ev & 0x3FFFFu) << 6) | (fl << 3)));
        float v = (float)(ev >> 18) * vs;
        acc8(a, v, q);
    }

    // --- 2-level transpose-butterfly over the 4 sub-groups (within 32-lane half) ---
    bool s0 = (sub & 1) != 0, s1 = (sub & 2) != 0;
    float b1[4];
    #pragma unroll
    for (int j = 0; j < 4; j++) {
        int c4 = (j >> 1) * 4, bb = j & 1;
        float keep = s0 ? a[c4 + 2 + bb] : a[c4 + bb];
        float send = s0 ? a[c4 + bb]     : a[c4 + 2 + bb];
        b1[j] = keep + __shfl_xor(send, 8, 64);
    }
    float cf[2];
    #pragma unroll
    for (int bb = 0; bb < 2; bb++) {
        float keep = s1 ? b1[2 + bb] : b1[bb];
        float send = s1 ? b1[bb]     : b1[2 + bb];
        cf[bb] = keep + __shfl_xor(send, 16, 64);
    }
    // lane now owns features fl*8 + 2*sub and fl*8 + 2*sub + 1 of this row
    float y0 = (cf[0] >= 0.f) ? cf[0] : NEG_SLOPE * cf[0];
    float y1 = (cf[1] >= 0.f) ? cf[1] : NEG_SLOPE * cf[1];
    float ss = fmaf(y0, y0, y1 * y1);
    ss += __shfl_xor(ss, 16, 64);
    ss += __shfl_xor(ss, 8, 64);
    ss += __shfl_xor(ss, 4, 64);
    ss += __shfl_xor(ss, 2, 64);
    ss += __shfl_xor(ss, 1, 64);
    float inv = 1.f / fmaxf(sqrtf(ss), EPS_NRM);
    __half2 o = __floats2half2_rn(y0 * inv, y1 * inv);
    *(__half2*)(pn + (size_t)row * D + fl * 8 + 2 * sub) = o;
}

// one wave per batch element: sum 4 layer rows for the user once, then 3 item dots.
__global__ void score_kernel(const int* __restrict__ users,
                             const int* __restrict__ it0,
                             const int* __restrict__ it1,
                             const int* __restrict__ it2,
                             const __half* __restrict__ p0,
                             const __half* __restrict__ p1,
                             const __half* __restrict__ p2,
                             const __half* __restrict__ p3,
                             float* __restrict__ out) {
    int b    = blockIdx.x * 4 + (threadIdx.x >> 6);
    int lane = threadIdx.x & 63;
    if (b >= BATCH) return;
    int u = users[b];
    size_t uo = (size_t)u * D + lane;
    float uf = __half2float(p0[uo]) + __half2float(p1[uo])
             + __half2float(p2[uo]) + __half2float(p3[uo]);

    int its[3];
    its[0] = it0[b]; its[1] = it1[b]; its[2] = it2[b];
    #pragma unroll
    for (int k = 0; k < 3; k++) {
        size_t io = (size_t)(NUM_USERS + its[k]) * D + lane;
        float itf = __half2float(p0[io]) + __half2float(p1[io])
                  + __half2float(p2[io]) + __half2float(p3[io]);
        float s = wave_sum64(uf * itf) * 0.0625f;
        if (lane == 0)
            out[k * BATCH + b] = 1.f / (1.f + expf(-s));
    }
}

extern "C" void kernel_launch(void* const* d_in, const int* in_sizes, int n_in,
                              void* d_out, int out_size, void* d_ws, size_t ws_size,
                              hipStream_t stream) {
    const int*   users  = (const int*)  d_in[0];
    const int*   adj    = (const int*)  d_in[1];
    const int*   weak   = (const int*)  d_in[2];
    const int*   strong = (const int*)  d_in[3];
    const int*   erows  = (const int*)  d_in[4];
    const int*   ecols  = (const int*)  d_in[5];
    const float* evals  = (const float*)d_in[6];
    const float* upref  = (const float*)d_in[7];
    const float* ipref  = (const float*)d_in[8];
    float* out = (float*)d_out;

    const size_t rowElems = (size_t)N_NODES * D;   // 9.6M

    char* base = (char*)d_ws;
    size_t off = 0;
    auto alloc = [&](size_t bytes) {
        char* p = base + off;
        off = (off + bytes + 255) & ~(size_t)255;
        return (void*)p;
    };
    __half*   p0      = (__half*)  alloc(rowElems * sizeof(__half));   // 19.2 MB
    __half*   p1      = (__half*)  alloc(rowElems * sizeof(__half));   // 19.2 MB
    __half*   p2      = (__half*)  alloc(rowElems * sizeof(__half));   // 19.2 MB
    __half*   p3      = (__half*)  alloc(rowElems * sizeof(__half));   // 19.2 MB
    unsigned* es      = (unsigned*)alloc((size_t)NB2 * CAPB * 4);      // 11.1 MB
    int2*     rowptr2 = (int2*)    alloc((size_t)N_NODES * sizeof(int2)); // 1.2 MB
    int*      gcur    = (int*)     alloc(NB2 * sizeof(int));
    // intermediate es8 (22.2 MB) aliases p2:p3 (38.4 MB contiguous): both are
    // first written by gather layers 2/3, stream-ordered after bucket_sort.
    uint2*    es8t    = (uint2*)p2;

    // ---- CSR build: direct-reservation bucket scatter, 2 dispatches ----
    hipMemsetAsync(gcur, 0, NB2 * sizeof(int), stream);
    scatter_init<<<NCHUNK + (N_NODES + 15) / 16, 1024, 0, stream>>>(
        erows, ecols, evals, gcur, es8t, upref, ipref, p0);
    bucket_sort<<<NB2 * 2, 512, 0, stream>>>(es8t, gcur, es, rowptr2);

    // ---- GCN layers (no acc array; layers kept separately in fp16) ----
    gather_kernel<<<N_NODES / 8, 256, 0, stream>>>(rowptr2, es, p0, p1);   // 150000 % 8 == 0
    gather_kernel<<<N_NODES / 8, 256, 0, stream>>>(rowptr2, es, p1, p2);
    gather_kernel<<<N_NODES / 8, 256, 0, stream>>>(rowptr2, es, p2, p3);

    score_kernel<<<(BATCH + 3) / 4, 256, 0, stream>>>(users, adj, weak, strong,
                                                      p0, p1, p2, p3, out);
}

// Round 12
// 313.518 us; speedup vs baseline: 1.0429x; 1.0429x over previous
//
#include <hip/hip_runtime.h>
#include <hip/hip_fp16.h>
#include <math.h>

#define D 64
#define NUM_USERS 100000
#define NUM_ITEMS 50000
#define N_NODES 150000   // NUM_USERS + NUM_ITEMS
#define NNZ 2400000
#define BATCH 8192
#define NEG_SLOPE 0.1f
#define EPS_NRM 1e-12f

// bucket geometry: bucket = row >> 9 (512 rows/bucket)
#define NB2     293                 // ceil(150000/512)
#define RPB     512                 // rows per bucket
#define NCHUNK  256
#define CH      9376                // chunk elems; 16B-aligned bases
#define CAPB    9472                // fixed per-bucket region (mean 8192, +14 sigma)
#define CAP     10240               // LDS sorted-buffer capacity (40 KB)
#define VSCALE  16383.f             // 14-bit val quantization

typedef unsigned short ushort_t;
// clang native vectors: __builtin_nontemporal_load requires these (HIP_vector_type invalid)
typedef int   iv4 __attribute__((ext_vector_type(4)));
typedef float fv4 __attribute__((ext_vector_type(4)));

__device__ __forceinline__ float wave_sum64(float v) {
    #pragma unroll
    for (int off = 32; off > 0; off >>= 1)
        v += __shfl_xor(v, off, 64);
    return v;
}

// fp16 helpers: extraction folds into v_fma_mix_f32 (op_sel) when fused.
__device__ __forceinline__ float h2f_lo(unsigned u) {
    return __half2float(__ushort_as_half((unsigned short)(u & 0xFFFFu)));
}
__device__ __forceinline__ float h2f_hi(unsigned u) {
    return __half2float(__ushort_as_half((unsigned short)(u >> 16)));
}

// ---------- CSR build: direct-reservation bucket scatter (no hist/scan kernels) ----
// Blocks [0, NCHUNK): per-chunk LDS count -> one global atomicAdd per bucket to
// reserve a run in the bucket's fixed CAPB region -> write 8B uint2 entries.
// Blocks [NCHUNK, ...): init (lrelu+L2norm of prefs -> fp16 p0), fills idle CUs.
__global__ void __launch_bounds__(1024) scatter_init(
        const int* __restrict__ rows, const int* __restrict__ cols,
        const float* __restrict__ vals, int* __restrict__ gcur,
        uint2* __restrict__ es8,
        const float* __restrict__ upref, const float* __restrict__ ipref,
        __half* __restrict__ p0) {
    __shared__ int cnt[NB2];
    __shared__ int cur[NB2];
    int blk = blockIdx.x, tid = threadIdx.x;

    if (blk >= NCHUNK) {
        // ---- init part: one row per wave, 16 rows per block ----
        int row  = (blk - NCHUNK) * 16 + (tid >> 6);
        int lane = tid & 63;
        if (row >= N_NODES) return;
        float x = (row < NUM_USERS) ? upref[(size_t)row * D + lane]
                                    : ipref[(size_t)(row - NUM_USERS) * D + lane];
        x = (x >= 0.f) ? x : NEG_SLOPE * x;
        float norm = sqrtf(wave_sum64(x * x));
        float y = x / fmaxf(norm, EPS_NRM);
        p0[(size_t)row * D + lane] = __float2half(y);
        return;
    }

    // ---- scatter part ----
    for (int b = tid; b < NB2; b += 1024) cnt[b] = 0;
    __syncthreads();
    int base = blk * CH;
    int n = NNZ - base; if (n > CH) n = CH;      // always divisible by 4
    const iv4* r4 = (const iv4*)(rows + base);
    for (int i = tid; i < (n >> 2); i += 1024) {
        iv4 r = r4[i];                           // normal load: L2-warm for pass 2
        atomicAdd(&cnt[r.x >> 9], 1);
        atomicAdd(&cnt[r.y >> 9], 1);
        atomicAdd(&cnt[r.z >> 9], 1);
        atomicAdd(&cnt[r.w >> 9], 1);
    }
    __syncthreads();
    if (tid < NB2) {
        int c = cnt[tid];
        int off = (c > 0) ? atomicAdd(&gcur[tid], c) : 0;   // reserve run
        cur[tid] = tid * CAPB + off;
    }
    __syncthreads();
    const iv4* c4 = (const iv4*)(cols + base);
    const fv4* v4 = (const fv4*)(vals + base);
    for (int i = tid; i < (n >> 2); i += 1024) {
        iv4 r  = r4[i];                          // L2 hit
        iv4 cc = __builtin_nontemporal_load(&c4[i]);
        fv4 v  = __builtin_nontemporal_load(&v4[i]);
        int p;
        p = atomicAdd(&cur[r.x >> 9], 1);
        es8[p] = make_uint2((unsigned)cc.x | ((unsigned)(v.x * VSCALE + 0.5f) << 18),
                            (unsigned)(r.x & (RPB - 1)));
        p = atomicAdd(&cur[r.y >> 9], 1);
        es8[p] = make_uint2((unsigned)cc.y | ((unsigned)(v.y * VSCALE + 0.5f) << 18),
                            (unsigned)(r.y & (RPB - 1)));
        p = atomicAdd(&cur[r.z >> 9], 1);
        es8[p] = make_uint2((unsigned)cc.z | ((unsigned)(v.z * VSCALE + 0.5f) << 18),
                            (unsigned)(r.z & (RPB - 1)));
        p = atomicAdd(&cur[r.w >> 9], 1);
        es8[p] = make_uint2((unsigned)cc.w | ((unsigned)(v.w * VSCALE + 0.5f) << 18),
                            (unsigned)(r.w & (RPB - 1)));
    }
}

// one block per bucket (~8192 edges in [b*CAPB, b*CAPB+fill)): hist on .y keys,
// 512-wide scan, permute 4B entries into LDS outbuf, coalesced dump.
// rowptr2 = int2 (beg,end) per row (es has inter-bucket gaps).
__global__ void __launch_bounds__(1024) bucket_sort(const uint2* __restrict__ es8,
                                                    const int* __restrict__ gcur,
                                                    unsigned* __restrict__ es,
                                                    int2* __restrict__ rowptr2) {
    __shared__ int      hist[RPB];
    __shared__ int      wsum[8];
    __shared__ unsigned outbuf[CAP];    // 40 KB
    int b = blockIdx.x, tid = threadIdx.x;
    int base = b * CAPB;
    int fill = gcur[b];
    int end  = base + fill;
    if (tid < RPB) hist[tid] = 0;
    __syncthreads();
    for (int i = base + tid; i < end; i += 1024)
        atomicAdd(&hist[es8[i].y], 1);
    __syncthreads();
    int excl = 0, v = 0;
    if (tid < RPB) {
        v = hist[tid];
        int lane = tid & 63, w = tid >> 6;
        int s = v;
        #pragma unroll
        for (int off = 1; off < 64; off <<= 1) {
            int t = __shfl_up(s, off, 64);
            if (lane >= off) s += t;
        }
        if (lane == 63) wsum[w] = s;
        excl = s - v;
    }
    __syncthreads();
    if (tid == 0) {
        int a = 0;
        #pragma unroll
        for (int i = 0; i < 8; i++) { int t = wsum[i]; wsum[i] = a; a += t; }
    }
    __syncthreads();
    if (tid < RPB) {
        excl += wsum[tid >> 6];
        int r = b * RPB + tid;
        if (r < N_NODES)
            rowptr2[r] = make_int2(base + excl, base + excl + v);
        hist[tid] = excl;           // reuse as cursor (bucket-relative)
    }
    __syncthreads();
    for (int i = base + tid; i < end; i += 1024) {
        uint2 kv = es8[i];                      // L2-warm re-read
        int d = atomicAdd(&hist[kv.y], 1);      // LDS int atomic
        outbuf[d] = kv.x;                       // final 4B format
    }
    __syncthreads();
    for (int i = tid; i < fill; i += 1024)
        es[base + i] = outbuf[i];               // coalesced dump
}

// ---------- GCN ----------
__device__ __forceinline__ void acc8(float a[8], float v, uint4 q) {
    a[0] = fmaf(v, h2f_lo(q.x), a[0]);
    a[1] = fmaf(v, h2f_hi(q.x), a[1]);
    a[2] = fmaf(v, h2f_lo(q.y), a[2]);
    a[3] = fmaf(v, h2f_hi(q.y), a[3]);
    a[4] = fmaf(v, h2f_lo(q.z), a[4]);
    a[5] = fmaf(v, h2f_hi(q.z), a[5]);
    a[6] = fmaf(v, h2f_lo(q.w), a[6]);
    a[7] = fmaf(v, h2f_hi(q.w), a[7]);
}

// TWO rows per wave (32 lanes each): 4 edge-slots (sub = hl>>3), 8 features/lane
// (fl = hl&7); 4-deep edge pipeline: 4 independent es->p load chains in flight
// (deg-16 rows finish a slot's work in ONE iteration). No launch_bounds cap:
// needs ~40 VGPR for the 4 uint4 in flight (round-6 test was strangled at 32).
// Epilogue: 2-level transpose-butterfly -> lane (sub,fl) holds ADJACENT features
// fl*8+2*sub, +1 -> one packed __half2 store.
__global__ void gather_kernel(const int2* __restrict__ rowptr2,
                              const unsigned* __restrict__ es,
                              const __half* __restrict__ p,
                              __half* __restrict__ pn) {
    int tid  = threadIdx.x;
    int row  = blockIdx.x * 8 + (tid >> 5);     // 8 rows per 256-thread block
    if (row >= N_NODES) return;
    int hl   = tid & 31;
    int sub  = hl >> 3;       // 0..3 edge slot
    int fl   = hl & 7;        // feature-octet index
    int2 rp  = rowptr2[row];
    int beg = rp.x, end = rp.y;

    float a[8];
    #pragma unroll
    for (int k = 0; k < 8; k++) a[k] = 0.f;

    const float vs = 1.f / VSCALE;
    int e = beg + sub;
    while (e + 12 < end) {
        unsigned ev0 = es[e];
        unsigned ev1 = es[e + 4];
        unsigned ev2 = es[e + 8];
        unsigned ev3 = es[e + 12];
        const uint4 q0 = *(const uint4*)(p + (((ev0 & 0x3FFFFu) << 6) | (fl << 3)));
        const uint4 q1 = *(const uint4*)(p + (((ev1 & 0x3FFFFu) << 6) | (fl << 3)));
        const uint4 q2 = *(const uint4*)(p + (((ev2 & 0x3FFFFu) << 6) | (fl << 3)));
        const uint4 q3 = *(const uint4*)(p + (((ev3 & 0x3FFFFu) << 6) | (fl << 3)));
        float v0 = (float)(ev0 >> 18) * vs;
        float v1 = (float)(ev1 >> 18) * vs;
        float v2 = (float)(ev2 >> 18) * vs;
        float v3 = (float)(ev3 >> 18) * vs;
        acc8(a, v0, q0);
        acc8(a, v1, q1);
        acc8(a, v2, q2);
        acc8(a, v3, q3);
        e += 16;
    }
    while (e + 4 < end) {
        unsigned ev0 = es[e];
        unsigned ev1 = es[e + 4];
        const uint4 q0 = *(const uint4*)(p + (((ev0 & 0x3FFFFu) << 6) | (fl << 3)));
        const uint4 q1 = *(const uint4*)(p + (((ev1 & 0x3FFFFu) << 6) | (fl << 3)));
        float v0 = (float)(ev0 >> 18) * vs;
        float v1 = (float)(ev1 >> 18) * vs;
        acc8(a, v0, q0);
        acc8(a, v1, q1);
        e += 8;
    }
    if (e < end) {
        unsigned ev = es[e];
        const uint4 q = *(const uint4*)(p + (((ev & 0x3FFFFu) << 6) | (fl << 3)));
        float v = (float)(ev >> 18) * vs;
        acc8(a, v, q);
    }

    // --- 2-level transpose-butterfly over the 4 sub-groups (within 32-lane half) ---
    bool s0 = (sub & 1) != 0, s1 = (sub & 2) != 0;
    float b1[4];
    #pragma unroll
    for (int j = 0; j < 4; j++) {
        int c4 = (j >> 1) * 4, bb = j & 1;
        float keep = s0 ? a[c4 + 2 + bb] : a[c4 + bb];
        float send = s0 ? a[c4 + bb]     : a[c4 + 2 + bb];
        b1[j] = keep + __shfl_xor(send, 8, 64);
    }
    float cf[2];
    #pragma unroll
    for (int bb = 0; bb < 2; bb++) {
        float keep = s1 ? b1[2 + bb] : b1[bb];
        float send = s1 ? b1[bb]     : b1[2 + bb];
        cf[bb] = keep + __shfl_xor(send, 16, 64);
    }
    // lane now owns features fl*8 + 2*sub and fl*8 + 2*sub + 1 of this row
    float y0 = (cf[0] >= 0.f) ? cf[0] : NEG_SLOPE * cf[0];
    float y1 = (cf[1] >= 0.f) ? cf[1] : NEG_SLOPE * cf[1];
    float ss = fmaf(y0, y0, y1 * y1);
    ss += __shfl_xor(ss, 16, 64);
    ss += __shfl_xor(ss, 8, 64);
    ss += __shfl_xor(ss, 4, 64);
    ss += __shfl_xor(ss, 2, 64);
    ss += __shfl_xor(ss, 1, 64);
    float inv = 1.f / fmaxf(sqrtf(ss), EPS_NRM);
    __half2 o = __floats2half2_rn(y0 * inv, y1 * inv);
    *(__half2*)(pn + (size_t)row * D + fl * 8 + 2 * sub) = o;
}

// one wave per batch element: sum 4 layer rows for the user once, then 3 item dots.
__global__ void score_kernel(const int* __restrict__ users,
                             const int* __restrict__ it0,
                             const int* __restrict__ it1,
                             const int* __restrict__ it2,
                             const __half* __restrict__ p0,
                             const __half* __restrict__ p1,
                             const __half* __restrict__ p2,
                             const __half* __restrict__ p3,
                             float* __restrict__ out) {
    int b    = blockIdx.x * 4 + (threadIdx.x >> 6);
    int lane = threadIdx.x & 63;
    if (b >= BATCH) return;
    int u = users[b];
    size_t uo = (size_t)u * D + lane;
    float uf = __half2float(p0[uo]) + __half2float(p1[uo])
             + __half2float(p2[uo]) + __half2float(p3[uo]);

    int its[3];
    its[0] = it0[b]; its[1] = it1[b]; its[2] = it2[b];
    #pragma unroll
    for (int k = 0; k < 3; k++) {
        size_t io = (size_t)(NUM_USERS + its[k]) * D + lane;
        float itf = __half2float(p0[io]) + __half2float(p1[io])
                  + __half2float(p2[io]) + __half2float(p3[io]);
        float s = wave_sum64(uf * itf) * 0.0625f;
        if (lane == 0)
            out[k * BATCH + b] = 1.f / (1.f + expf(-s));
    }
}

extern "C" void kernel_launch(void* const* d_in, const int* in_sizes, int n_in,
                              void* d_out, int out_size, void* d_ws, size_t ws_size,
                              hipStream_t stream) {
    const int*   users  = (const int*)  d_in[0];
    const int*   adj    = (const int*)  d_in[1];
    const int*   weak   = (const int*)  d_in[2];
    const int*   strong = (const int*)  d_in[3];
    const int*   erows  = (const int*)  d_in[4];
    const int*   ecols  = (const int*)  d_in[5];
    const float* evals  = (const float*)d_in[6];
    const float* upref  = (const float*)d_in[7];
    const float* ipref  = (const float*)d_in[8];
    float* out = (float*)d_out;

    const size_t rowElems = (size_t)N_NODES * D;   // 9.6M

    char* base = (char*)d_ws;
    size_t off = 0;
    auto alloc = [&](size_t bytes) {
        char* p = base + off;
        off = (off + bytes + 255) & ~(size_t)255;
        return (void*)p;
    };
    __half*   p0      = (__half*)  alloc(rowElems * sizeof(__half));   // 19.2 MB
    __half*   p1      = (__half*)  alloc(rowElems * sizeof(__half));   // 19.2 MB
    __half*   p2      = (__half*)  alloc(rowElems * sizeof(__half));   // 19.2 MB
    __half*   p3      = (__half*)  alloc(rowElems * sizeof(__half));   // 19.2 MB
    unsigned* es      = (unsigned*)alloc((size_t)NB2 * CAPB * 4);      // 11.1 MB
    int2*     rowptr2 = (int2*)    alloc((size_t)N_NODES * sizeof(int2)); // 1.2 MB
    int*      gcur    = (int*)     alloc(NB2 * sizeof(int));
    // intermediate es8 (22.2 MB) aliases p2:p3 (38.4 MB contiguous): both are
    // first written by gather layers 2/3, stream-ordered after bucket_sort.
    uint2*    es8t    = (uint2*)p2;

    // ---- CSR build: direct-reservation bucket scatter, 2 dispatches ----
    hipMemsetAsync(gcur, 0, NB2 * sizeof(int), stream);
    scatter_init<<<NCHUNK + (N_NODES + 15) / 16, 1024, 0, stream>>>(
        erows, ecols, evals, gcur, es8t, upref, ipref, p0);
    bucket_sort<<<NB2, 1024, 0, stream>>>(es8t, gcur, es, rowptr2);

    // ---- GCN layers (no acc array; layers kept separately in fp16) ----
    gather_kernel<<<N_NODES / 8, 256, 0, stream>>>(rowptr2, es, p0, p1);   // 150000 % 8 == 0
    gather_kernel<<<N_NODES / 8, 256, 0, stream>>>(rowptr2, es, p1, p2);
    gather_kernel<<<N_NODES / 8, 256, 0, stream>>>(rowptr2, es, p2, p3);

    score_kernel<<<(BATCH + 3) / 4, 256, 0, stream>>>(users, adj, weak, strong,
                                                      p0, p1, p2, p3, out);
}